// Round 2
// baseline (214.651 us; speedup 1.0000x reference)
//
#include <hip/hip_runtime.h>
#include <hip/hip_bf16.h>
#include <math.h>

// GAT, N=4096, NFEAT=512, NHID=64, NHEADS=8, NCLASS=41, EDGE_P=0.004.
// Adjacency has ~17 nonzeros/row -> both attention layers are exactly sparse
// (masked entries get exp(-9e15 - max) == 0). Build ELL neighbor lists once,
// then both layers are tiny gather/softmax/accumulate ops.
// ALL inputs/outputs are fp32 (reference uses jnp.float32 everywhere; round-1
// NaN came from misreading fp32 as bf16).

#define N 4096
#define NFEAT 512
#define NHID 64
#define NHEADS 8
#define NCLASS 41
#define ALPHA 0.2f
#define ELLW 128   // max neighbors kept; Binomial(4096,0.004) ~ 17 +/- 4, P(>128)~0

__device__ __forceinline__ float wred_max(float v) {
#pragma unroll
  for (int o = 32; o; o >>= 1) v = fmaxf(v, __shfl_xor(v, o, 64));
  return v;
}
__device__ __forceinline__ float wred_sum(float v) {
#pragma unroll
  for (int o = 32; o; o >>= 1) v += __shfl_xor(v, o, 64);
  return v;
}

// ---------------------------------------------------------------- build ELL
__global__ __launch_bounds__(256) void build_ell(const float* __restrict__ adj,
                                                 int* __restrict__ cols,
                                                 int* __restrict__ cnts) {
  __shared__ int c;
  const int row = blockIdx.x;
  if (threadIdx.x == 0) c = 0;
  __syncthreads();
  const float4* arow = (const float4*)(adj + (size_t)row * N);
  for (int j4 = threadIdx.x; j4 < N / 4; j4 += 256) {
    float4 v = arow[j4];
    // preserve column order within the lane's quad; order across lanes is
    // arbitrary but softmax/weighted-sum are order-insensitive (fp32 assoc
    // noise only).
    if (v.x > 0.f) { int p = atomicAdd(&c, 1); if (p < ELLW) cols[row * ELLW + p] = j4 * 4 + 0; }
    if (v.y > 0.f) { int p = atomicAdd(&c, 1); if (p < ELLW) cols[row * ELLW + p] = j4 * 4 + 1; }
    if (v.z > 0.f) { int p = atomicAdd(&c, 1); if (p < ELLW) cols[row * ELLW + p] = j4 * 4 + 2; }
    if (v.w > 0.f) { int p = atomicAdd(&c, 1); if (p < ELLW) cols[row * ELLW + p] = j4 * 4 + 3; }
  }
  __syncthreads();
  if (threadIdx.x == 0) cnts[row] = min(c, ELLW);
}

// ------------------------------------------------- Wh = x @ W_heads (per head)
// 64x64 output tile per block, k-chunks of 32 staged in LDS, 4x4 microtile.
__global__ __launch_bounds__(256) void wh_gemm(const float* __restrict__ x,
                                               const float* __restrict__ Wm,
                                               float* __restrict__ Wh) {
  __shared__ float xs[64][33];
  __shared__ float wsh[32][65];
  const int h = blockIdx.y;
  const int n0 = blockIdx.x * 64;
  const int tid = threadIdx.x;
  const int tx = tid & 15;   // d-group (4 cols)
  const int ty = tid >> 4;   // n-group (4 rows)
  const float* Wp = Wm + (size_t)h * NFEAT * NHID;
  float acc[4][4] = {};
  for (int k0 = 0; k0 < NFEAT; k0 += 32) {
#pragma unroll
    for (int i = 0; i < 8; i++) {
      int e = tid + 256 * i;            // 2048 elements each
      int xr = e >> 5, xk = e & 31;
      xs[xr][xk] = x[(size_t)(n0 + xr) * NFEAT + k0 + xk];
      int wk = e >> 6, wd = e & 63;
      wsh[wk][wd] = Wp[(size_t)(k0 + wk) * NHID + wd];
    }
    __syncthreads();
#pragma unroll 8
    for (int kk = 0; kk < 32; kk++) {
      float xa[4], wb[4];
#pragma unroll
      for (int i = 0; i < 4; i++) xa[i] = xs[ty * 4 + i][kk];
#pragma unroll
      for (int j = 0; j < 4; j++) wb[j] = wsh[kk][tx * 4 + j];
#pragma unroll
      for (int i = 0; i < 4; i++)
#pragma unroll
        for (int j = 0; j < 4; j++) acc[i][j] += xa[i] * wb[j];
    }
    __syncthreads();
  }
#pragma unroll
  for (int i = 0; i < 4; i++)
#pragma unroll
    for (int j = 0; j < 4; j++)
      Wh[((size_t)(h << 12) + n0 + ty * 4 + i) * NHID + tx * 4 + j] = acc[i][j];
}

// ------------------------------------------------------- s1/s2 per (head,node)
__global__ __launch_bounds__(256) void s12_kernel(const float* __restrict__ Wh,
                                                  const float* __restrict__ a_heads,
                                                  float* __restrict__ s1,
                                                  float* __restrict__ s2) {
  const int pair = blockIdx.x * 4 + (threadIdx.x >> 6);  // pair = h*N + n
  const int lane = threadIdx.x & 63;
  const int h = pair >> 12;
  float v = Wh[(size_t)pair * NHID + lane];
  float r1 = v * a_heads[h * 2 * NHID + lane];
  float r2 = v * a_heads[h * 2 * NHID + NHID + lane];
  r1 = wred_sum(r1);
  r2 = wred_sum(r2);
  if (lane == 0) { s1[pair] = r1; s2[pair] = r2; }
}

// ------------------------------------- layer-1 sparse attention + ELU -> hbuf
__global__ __launch_bounds__(256) void att1_kernel(const float* __restrict__ Wh,
                                                   const float* __restrict__ s1,
                                                   const float* __restrict__ s2,
                                                   const int* __restrict__ cols,
                                                   const int* __restrict__ cnts,
                                                   float* __restrict__ hbuf) {
  __shared__ float pj[4][ELLW];
  __shared__ int jj[4][ELLW];
  const int w = threadIdx.x >> 6, lane = threadIdx.x & 63;
  const int pair = blockIdx.x * 4 + w;
  const int h = pair >> 12, i = pair & (N - 1);
  const int cnt = min(cnts[i], ELLW);
  const float s1i = s1[pair];
  const float* s2h = s2 + (h << 12);
  float e0 = -1e30f, e1 = -1e30f;
  int j0 = 0, j1 = 0;
  if (lane < cnt) {
    j0 = cols[i * ELLW + lane];
    float t = s1i + s2h[j0];
    e0 = t > 0.f ? t : ALPHA * t;
  }
  if (lane + 64 < cnt) {
    j1 = cols[i * ELLW + lane + 64];
    float t = s1i + s2h[j1];
    e1 = t > 0.f ? t : ALPHA * t;
  }
  const float m = wred_max(fmaxf(e0, e1));
  const float p0 = (lane < cnt) ? expf(e0 - m) : 0.f;
  const float p1 = (lane + 64 < cnt) ? expf(e1 - m) : 0.f;
  const float S = wred_sum(p0 + p1);
  const float inv = 1.f / S;
  if (lane < cnt) { pj[w][lane] = p0 * inv; jj[w][lane] = j0; }
  if (lane + 64 < cnt) { pj[w][lane + 64] = p1 * inv; jj[w][lane + 64] = j1; }
  __syncthreads();
  const float* Whh = Wh + ((size_t)(h << 12)) * NHID;
  float acc = 0.f;
  for (int t = 0; t < cnt; t++)
    acc += pj[w][t] * Whh[(size_t)jj[w][t] * NHID + lane];
  float o = acc > 0.f ? acc : expf(acc) - 1.f;  // ELU
  hbuf[(size_t)i * (NHEADS * NHID) + h * NHID + lane] = o;
}

// ------------------------------ Wh2 = h @ W_out, plus s1_2/s2_2 per node
__global__ __launch_bounds__(64) void wh2_kernel(const float* __restrict__ hbuf,
                                                 const float* __restrict__ W_out,
                                                 const float* __restrict__ a_out,
                                                 float* __restrict__ Wh2,
                                                 float* __restrict__ s1b,
                                                 float* __restrict__ s2b) {
  __shared__ float hrow[NHEADS * NHID];
  const int n = blockIdx.x, tid = threadIdx.x;
  for (int k = tid; k < NHEADS * NHID; k += 64)
    hrow[k] = hbuf[(size_t)n * (NHEADS * NHID) + k];
  __syncthreads();
  float acc = 0.f;
  if (tid < NCLASS) {
    for (int k = 0; k < NHEADS * NHID; k++)
      acc += hrow[k] * W_out[k * NCLASS + tid];
  }
  float r1 = (tid < NCLASS) ? acc * a_out[tid] : 0.f;
  float r2 = (tid < NCLASS) ? acc * a_out[NCLASS + tid] : 0.f;
  r1 = wred_sum(r1);
  r2 = wred_sum(r2);
  if (tid < NCLASS) Wh2[n * NCLASS + tid] = acc;
  if (tid == 0) { s1b[n] = r1; s2b[n] = r2; }
}

// ----------------- layer-2 sparse attention + ELU + log_softmax -> out (fp32)
__global__ __launch_bounds__(256) void att2_kernel(const float* __restrict__ Wh2,
                                                   const float* __restrict__ s1b,
                                                   const float* __restrict__ s2b,
                                                   const int* __restrict__ cols,
                                                   const int* __restrict__ cnts,
                                                   float* __restrict__ out) {
  __shared__ float pj[4][ELLW];
  __shared__ int jj[4][ELLW];
  const int w = threadIdx.x >> 6, lane = threadIdx.x & 63;
  const int i = blockIdx.x * 4 + w;
  const int cnt = min(cnts[i], ELLW);
  const float s1i = s1b[i];
  float e0 = -1e30f, e1 = -1e30f;
  int j0 = 0, j1 = 0;
  if (lane < cnt) {
    j0 = cols[i * ELLW + lane];
    float t = s1i + s2b[j0];
    e0 = t > 0.f ? t : ALPHA * t;
  }
  if (lane + 64 < cnt) {
    j1 = cols[i * ELLW + lane + 64];
    float t = s1i + s2b[j1];
    e1 = t > 0.f ? t : ALPHA * t;
  }
  const float m = wred_max(fmaxf(e0, e1));
  const float p0 = (lane < cnt) ? expf(e0 - m) : 0.f;
  const float p1 = (lane + 64 < cnt) ? expf(e1 - m) : 0.f;
  const float S = wred_sum(p0 + p1);
  const float inv = 1.f / S;
  if (lane < cnt) { pj[w][lane] = p0 * inv; jj[w][lane] = j0; }
  if (lane + 64 < cnt) { pj[w][lane + 64] = p1 * inv; jj[w][lane + 64] = j1; }
  __syncthreads();
  float acc = 0.f;
  for (int t = 0; t < cnt; t++) {
    if (lane < NCLASS) acc += pj[w][t] * Wh2[(size_t)jj[w][t] * NCLASS + lane];
  }
  float o = acc > 0.f ? acc : expf(acc) - 1.f;  // ELU
  // log_softmax over the 41 classes (in-wave)
  float vv = (lane < NCLASS) ? o : -1e30f;
  const float mm = wred_max(vv);
  const float ex = (lane < NCLASS) ? expf(o - mm) : 0.f;
  const float SS = wred_sum(ex);
  if (lane < NCLASS) out[(size_t)i * NCLASS + lane] = o - mm - logf(SS);
}

// ---------------------------------------------------------------------------
extern "C" void kernel_launch(void* const* d_in, const int* in_sizes, int n_in,
                              void* d_out, int out_size, void* d_ws, size_t ws_size,
                              hipStream_t stream) {
  const float* x       = (const float*)d_in[0];   // (4096, 512)
  const float* adj     = (const float*)d_in[1];   // (4096, 4096)
  const float* W_heads = (const float*)d_in[2];   // (8, 512, 64)
  const float* a_heads = (const float*)d_in[3];   // (8, 128, 1)
  const float* W_out   = (const float*)d_in[4];   // (512, 41)
  const float* a_out   = (const float*)d_in[5];   // (82, 1)
  float* out = (float*)d_out;                     // (4096, 41)

  // workspace layout (fp32), ~20 MB total
  float* ws   = (float*)d_ws;
  float* Wh   = ws;                                  // 8*4096*64
  float* s1   = Wh + (size_t)NHEADS * N * NHID;      // 8*4096
  float* s2   = s1 + NHEADS * N;                     // 8*4096
  float* hbuf = s2 + NHEADS * N;                     // 4096*512
  float* Wh2  = hbuf + (size_t)N * NHEADS * NHID;    // 4096*41
  float* s1b  = Wh2 + (size_t)N * NCLASS;            // 4096
  float* s2b  = s1b + N;                             // 4096
  int* cnts   = (int*)(s2b + N);                     // 4096
  int* cols   = cnts + N;                            // 4096*128

  hipLaunchKernelGGL(build_ell, dim3(N), dim3(256), 0, stream, adj, cols, cnts);
  hipLaunchKernelGGL(wh_gemm, dim3(N / 64, NHEADS), dim3(256), 0, stream, x, W_heads, Wh);
  hipLaunchKernelGGL(s12_kernel, dim3(NHEADS * N / 4), dim3(256), 0, stream, Wh, a_heads, s1, s2);
  hipLaunchKernelGGL(att1_kernel, dim3(NHEADS * N / 4), dim3(256), 0, stream, Wh, s1, s2, cols, cnts, hbuf);
  hipLaunchKernelGGL(wh2_kernel, dim3(N), dim3(64), 0, stream, hbuf, W_out, a_out, Wh2, s1b, s2b);
  hipLaunchKernelGGL(att2_kernel, dim3(N / 4), dim3(256), 0, stream, Wh2, s1b, s2b, cols, cnts, out);
}

// Round 3
// 175.436 us; speedup vs baseline: 1.2235x; 1.2235x over previous
//
#include <hip/hip_runtime.h>
#include <hip/hip_bf16.h>
#include <math.h>

// GAT, N=4096, NFEAT=512, NHID=64, NHEADS=8, NCLASS=41, EDGE_P=0.004.
// Adjacency ~17 nnz/row -> both attention layers are exactly sparse.
// Layer-1 GEMM (x @ W_heads, 2.15 GFLOP) now uses bf16 MFMA with split-bf16
// (hi+lo) 3-term products for fp32-grade accuracy; s1/s2 fused into epilogue.

#define N 4096
#define NFEAT 512
#define NHID 64
#define NHEADS 8
#define NCLASS 41
#define ALPHA 0.2f
#define ELLW 64   // Binomial(4096,0.004): mean 16.4, P(cnt>64) ~ 1e-18

using short8  = __attribute__((ext_vector_type(8))) short;
using floatx4 = __attribute__((ext_vector_type(4))) float;

__device__ __forceinline__ float wred_max(float v) {
#pragma unroll
  for (int o = 32; o; o >>= 1) v = fmaxf(v, __shfl_xor(v, o, 64));
  return v;
}
__device__ __forceinline__ float wred_sum(float v) {
#pragma unroll
  for (int o = 32; o; o >>= 1) v += __shfl_xor(v, o, 64);
  return v;
}

__device__ __forceinline__ void split_bf16(float v, short& hi, short& lo) {
  __hip_bfloat16 hb = __float2bfloat16(v);
  float hf = __bfloat162float(hb);
  __hip_bfloat16 lb = __float2bfloat16(v - hf);
  hi = *reinterpret_cast<short*>(&hb);
  lo = *reinterpret_cast<short*>(&lb);
}

// ---------------------------------------------------------------- build ELL
__global__ __launch_bounds__(256) void build_ell(const float* __restrict__ adj,
                                                 int* __restrict__ cols,
                                                 int* __restrict__ cnts) {
  __shared__ int c;
  const int row = blockIdx.x;
  if (threadIdx.x == 0) c = 0;
  __syncthreads();
  const float4* arow = (const float4*)(adj + (size_t)row * N);
  for (int j4 = threadIdx.x; j4 < N / 4; j4 += 256) {
    float4 v = arow[j4];
    if (v.x > 0.f) { int p = atomicAdd(&c, 1); if (p < ELLW) cols[row * ELLW + p] = j4 * 4 + 0; }
    if (v.y > 0.f) { int p = atomicAdd(&c, 1); if (p < ELLW) cols[row * ELLW + p] = j4 * 4 + 1; }
    if (v.z > 0.f) { int p = atomicAdd(&c, 1); if (p < ELLW) cols[row * ELLW + p] = j4 * 4 + 2; }
    if (v.w > 0.f) { int p = atomicAdd(&c, 1); if (p < ELLW) cols[row * ELLW + p] = j4 * 4 + 3; }
  }
  __syncthreads();
  if (threadIdx.x == 0) cnts[row] = min(c, ELLW);
}

// -------------------- split W_heads (h,k,d) -> bf16 hi/lo transposed (h,d,k)
__global__ __launch_bounds__(256) void convert_w(const float* __restrict__ W,
                                                 short* __restrict__ Wthi,
                                                 short* __restrict__ Wtlo) {
  const int t = blockIdx.x * 256 + threadIdx.x;   // 0..262143
  const int h = t >> 15, r = t & 32767;
  const int d = r >> 9, k = r & 511;              // write-coalesced mapping
  float v = W[(size_t)h * 32768 + (size_t)k * 64 + d];
  short hi, lo;
  split_bf16(v, hi, lo);
  Wthi[(size_t)h * 32768 + d * 512 + k] = hi;
  Wtlo[(size_t)h * 32768 + d * 512 + k] = lo;
}

// ----------------- Wh = x @ W_heads via split-bf16 MFMA; fused s1/s2 epilogue
// Block: 256 thr (4 waves), tile 64 rows x 64 cols, K-chunks of 64.
// Wave w computes rows [n0+16w, n0+16w+16) x all 64 cols (4 col-frags).
// MFMA 16x16x32 bf16: A[m=lane&15][k=(lane>>4)*8+j]; B[n=lane&15][k likewise];
// C/D: col=lane&15, row=(lane>>4)*4+reg.  LDS rows padded to 72 bf16 (144 B).
__global__ __launch_bounds__(256) void wh_gemm_mfma(
    const float* __restrict__ x, const short* __restrict__ Wthi,
    const short* __restrict__ Wtlo, const float* __restrict__ a_heads,
    float* __restrict__ Wh, float* __restrict__ s1, float* __restrict__ s2) {
  __shared__ __align__(16) short Ahi[64 * 72];
  __shared__ __align__(16) short Alo[64 * 72];
  __shared__ __align__(16) short Bhi[64 * 72];
  __shared__ __align__(16) short Blo[64 * 72];
  const int h = blockIdx.y;
  const int n0 = blockIdx.x * 64;
  const int tid = threadIdx.x;
  const int w = tid >> 6, L = tid & 63;
  const short* Wph = Wthi + (size_t)h * 32768;   // [d][k]
  const short* Wpl = Wtlo + (size_t)h * 32768;

  floatx4 acc[4];
#pragma unroll
  for (int f = 0; f < 4; f++) acc[f] = (floatx4){0.f, 0.f, 0.f, 0.f};

  for (int k0 = 0; k0 < NFEAT; k0 += 64) {
    __syncthreads();   // previous iter's frag reads done before re-staging
#pragma unroll
    for (int i = 0; i < 2; i++) {
      const int g = tid + 256 * i;       // 0..511 -> (row, 8-elem k group)
      const int row = g >> 3, kg = (g & 7) * 8;
      // A: split x on the fly
      const float* src = &x[(size_t)(n0 + row) * NFEAT + k0 + kg];
      short8 vhi, vlo;
#pragma unroll
      for (int e = 0; e < 8; e++) {
        short hi, lo;
        split_bf16(src[e], hi, lo);
        vhi[e] = hi; vlo[e] = lo;
      }
      *(short8*)&Ahi[row * 72 + kg] = vhi;
      *(short8*)&Alo[row * 72 + kg] = vlo;
      // B: pre-split, pre-transposed
      *(uint4*)&Bhi[row * 72 + kg] = *(const uint4*)&Wph[(size_t)row * 512 + k0 + kg];
      *(uint4*)&Blo[row * 72 + kg] = *(const uint4*)&Wpl[(size_t)row * 512 + k0 + kg];
    }
    __syncthreads();
#pragma unroll
    for (int ks = 0; ks < 2; ks++) {
      const int koff = ks * 32 + (L >> 4) * 8;
      short8 ahi = *(const short8*)&Ahi[(w * 16 + (L & 15)) * 72 + koff];
      short8 alo = *(const short8*)&Alo[(w * 16 + (L & 15)) * 72 + koff];
#pragma unroll
      for (int f = 0; f < 4; f++) {
        short8 bhi = *(const short8*)&Bhi[(f * 16 + (L & 15)) * 72 + koff];
        short8 blo = *(const short8*)&Blo[(f * 16 + (L & 15)) * 72 + koff];
        acc[f] = __builtin_amdgcn_mfma_f32_16x16x32_bf16(ahi, bhi, acc[f], 0, 0, 0);
        acc[f] = __builtin_amdgcn_mfma_f32_16x16x32_bf16(ahi, blo, acc[f], 0, 0, 0);
        acc[f] = __builtin_amdgcn_mfma_f32_16x16x32_bf16(alo, bhi, acc[f], 0, 0, 0);
      }
    }
  }

  // Epilogue: write Wh (fp32) + fused s1/s2 = Wh . a1 / a2
  const int q = L >> 4, c16 = L & 15;
  float a1v[4], a2v[4];
#pragma unroll
  for (int f = 0; f < 4; f++) {
    a1v[f] = a_heads[h * 128 + f * 16 + c16];
    a2v[f] = a_heads[h * 128 + 64 + f * 16 + c16];
  }
  float p1[4] = {0.f, 0.f, 0.f, 0.f}, p2[4] = {0.f, 0.f, 0.f, 0.f};
#pragma unroll
  for (int f = 0; f < 4; f++)
#pragma unroll
    for (int r = 0; r < 4; r++) {
      const float vv = acc[f][r];
      const int row = n0 + w * 16 + q * 4 + r;
      Wh[((size_t)(h << 12) + row) * NHID + f * 16 + c16] = vv;
      p1[r] += vv * a1v[f];
      p2[r] += vv * a2v[f];
    }
#pragma unroll
  for (int r = 0; r < 4; r++)
#pragma unroll
    for (int o = 1; o < 16; o <<= 1) {
      p1[r] += __shfl_xor(p1[r], o, 64);
      p2[r] += __shfl_xor(p2[r], o, 64);
    }
  if (c16 == 0) {
    const int row = n0 + w * 16 + q * 4;
#pragma unroll
    for (int r = 0; r < 4; r++) {
      s1[(h << 12) + row + r] = p1[r];
      s2[(h << 12) + row + r] = p2[r];
    }
  }
}

// ------------------------------------- layer-1 sparse attention + ELU -> hbuf
__global__ __launch_bounds__(256) void att1_kernel(const float* __restrict__ Wh,
                                                   const float* __restrict__ s1,
                                                   const float* __restrict__ s2,
                                                   const int* __restrict__ cols,
                                                   const int* __restrict__ cnts,
                                                   float* __restrict__ hbuf) {
  __shared__ float pj[4][ELLW];
  __shared__ int jj[4][ELLW];
  const int w = threadIdx.x >> 6, lane = threadIdx.x & 63;
  const int pair = blockIdx.x * 4 + w;
  const int h = pair >> 12, i = pair & (N - 1);
  const int cnt = min(cnts[i], ELLW);
  const float s1i = s1[pair];
  const float* s2h = s2 + (h << 12);
  float e0 = -1e30f;
  int j0 = 0;
  if (lane < cnt) {
    j0 = cols[i * ELLW + lane];
    float t = s1i + s2h[j0];
    e0 = t > 0.f ? t : ALPHA * t;
  }
  const float m = wred_max(e0);
  const float p0 = (lane < cnt) ? expf(e0 - m) : 0.f;
  const float S = wred_sum(p0);
  const float inv = 1.f / S;
  if (lane < cnt) { pj[w][lane] = p0 * inv; jj[w][lane] = j0; }
  __syncthreads();
  const float* Whh = Wh + ((size_t)(h << 12)) * NHID;
  float acc = 0.f;
  for (int t = 0; t < cnt; t++)
    acc += pj[w][t] * Whh[(size_t)jj[w][t] * NHID + lane];
  float o = acc > 0.f ? acc : expf(acc) - 1.f;  // ELU
  hbuf[(size_t)i * (NHEADS * NHID) + h * NHID + lane] = o;
}

// ------------------------------ Wh2 = h @ W_out, plus s1_2/s2_2 per node
__global__ __launch_bounds__(64) void wh2_kernel(const float* __restrict__ hbuf,
                                                 const float* __restrict__ W_out,
                                                 const float* __restrict__ a_out,
                                                 float* __restrict__ Wh2,
                                                 float* __restrict__ s1b,
                                                 float* __restrict__ s2b) {
  __shared__ float hrow[NHEADS * NHID];
  const int n = blockIdx.x, tid = threadIdx.x;
  for (int k = tid; k < NHEADS * NHID; k += 64)
    hrow[k] = hbuf[(size_t)n * (NHEADS * NHID) + k];
  __syncthreads();
  float acc = 0.f;
  if (tid < NCLASS) {
    for (int k = 0; k < NHEADS * NHID; k++)
      acc += hrow[k] * W_out[k * NCLASS + tid];
  }
  float r1 = (tid < NCLASS) ? acc * a_out[tid] : 0.f;
  float r2 = (tid < NCLASS) ? acc * a_out[NCLASS + tid] : 0.f;
  r1 = wred_sum(r1);
  r2 = wred_sum(r2);
  if (tid < NCLASS) Wh2[n * NCLASS + tid] = acc;
  if (tid == 0) { s1b[n] = r1; s2b[n] = r2; }
}

// ----------------- layer-2 sparse attention + ELU + log_softmax -> out (fp32)
__global__ __launch_bounds__(256) void att2_kernel(const float* __restrict__ Wh2,
                                                   const float* __restrict__ s1b,
                                                   const float* __restrict__ s2b,
                                                   const int* __restrict__ cols,
                                                   const int* __restrict__ cnts,
                                                   float* __restrict__ out) {
  __shared__ float pj[4][ELLW];
  __shared__ int jj[4][ELLW];
  const int w = threadIdx.x >> 6, lane = threadIdx.x & 63;
  const int i = blockIdx.x * 4 + w;
  const int cnt = min(cnts[i], ELLW);
  const float s1i = s1b[i];
  float e0 = -1e30f;
  int j0 = 0;
  if (lane < cnt) {
    j0 = cols[i * ELLW + lane];
    float t = s1i + s2b[j0];
    e0 = t > 0.f ? t : ALPHA * t;
  }
  const float m = wred_max(e0);
  const float p0 = (lane < cnt) ? expf(e0 - m) : 0.f;
  const float S = wred_sum(p0);
  const float inv = 1.f / S;
  if (lane < cnt) { pj[w][lane] = p0 * inv; jj[w][lane] = j0; }
  __syncthreads();
  float acc = 0.f;
  for (int t = 0; t < cnt; t++) {
    if (lane < NCLASS) acc += pj[w][t] * Wh2[(size_t)jj[w][t] * NCLASS + lane];
  }
  float o = acc > 0.f ? acc : expf(acc) - 1.f;  // ELU
  float vv = (lane < NCLASS) ? o : -1e30f;
  const float mm = wred_max(vv);
  const float ex = (lane < NCLASS) ? expf(o - mm) : 0.f;
  const float SS = wred_sum(ex);
  if (lane < NCLASS) out[(size_t)i * NCLASS + lane] = o - mm - logf(SS);
}

// ---------------------------------------------------------------------------
extern "C" void kernel_launch(void* const* d_in, const int* in_sizes, int n_in,
                              void* d_out, int out_size, void* d_ws, size_t ws_size,
                              hipStream_t stream) {
  const float* x       = (const float*)d_in[0];   // (4096, 512)
  const float* adj     = (const float*)d_in[1];   // (4096, 4096)
  const float* W_heads = (const float*)d_in[2];   // (8, 512, 64)
  const float* a_heads = (const float*)d_in[3];   // (8, 128, 1)
  const float* W_out   = (const float*)d_in[4];   // (512, 41)
  const float* a_out   = (const float*)d_in[5];   // (82, 1)
  float* out = (float*)d_out;                     // (4096, 41)

  // workspace layout (~21 MB)
  float* ws   = (float*)d_ws;
  float* Wh   = ws;                                  // 8*4096*64
  float* s1   = Wh + (size_t)NHEADS * N * NHID;      // 8*4096
  float* s2   = s1 + NHEADS * N;                     // 8*4096
  float* hbuf = s2 + NHEADS * N;                     // 4096*512
  float* Wh2  = hbuf + (size_t)N * NHEADS * NHID;    // 4096*41
  float* s1b  = Wh2 + (size_t)N * NCLASS;            // 4096
  float* s2b  = s1b + N;                             // 4096
  int* cnts   = (int*)(s2b + N);                     // 4096
  int* cols   = cnts + N;                            // 4096*64
  short* Wthi = (short*)(cols + N * ELLW);           // 8*64*512 bf16 hi
  short* Wtlo = Wthi + (size_t)NHEADS * NHID * NFEAT;// 8*64*512 bf16 lo

  hipLaunchKernelGGL(build_ell, dim3(N), dim3(256), 0, stream, adj, cols, cnts);
  hipLaunchKernelGGL(convert_w, dim3(1024), dim3(256), 0, stream, W_heads, Wthi, Wtlo);
  hipLaunchKernelGGL(wh_gemm_mfma, dim3(N / 64, NHEADS), dim3(256), 0, stream,
                     x, Wthi, Wtlo, a_heads, Wh, s1, s2);
  hipLaunchKernelGGL(att1_kernel, dim3(NHEADS * N / 4), dim3(256), 0, stream, Wh, s1, s2, cols, cnts, hbuf);
  hipLaunchKernelGGL(wh2_kernel, dim3(N), dim3(64), 0, stream, hbuf, W_out, a_out, Wh2, s1b, s2b);
  hipLaunchKernelGGL(att2_kernel, dim3(N / 4), dim3(256), 0, stream, Wh2, s1b, s2b, cols, cnts, out);
}